// Round 2
// baseline (149.872 us; speedup 1.0000x reference)
//
#include <hip/hip_runtime.h>
#include <hip/hip_bf16.h>

// ============================================================================
// ROUND 2: INSTRUMENTATION BUILD.
//   proj K-loop repeated x5 (result scaled by 0.2 -> identical output),
//   attn phase-1 repeated x2 (O and ls both double -> normalization cancels).
//   Base pointers laundered via empty asm each rep to defeat load CSE/hoist.
// Purpose: dur_us delta = 4*proj_warm + 1*attn_phase1, disambiguating
// "harness fill overhead dominates" vs "kernels are ~40us each".  If proj
// crosses ~45us it surfaces in the top-5 table WITH counters.
// ============================================================================

#define B_ 8
#define D_ 128
#define NH 8
#define L_ 1024
#define DK 16

#define REPS_PROJ 5
#define REPS_ATTN 2

typedef __attribute__((ext_vector_type(4))) short s4;
typedef __attribute__((ext_vector_type(4))) float f4;

static __device__ __forceinline__ unsigned short f2bf(float f) {
    __hip_bfloat16 h = __float2bfloat16(f);
    return *reinterpret_cast<unsigned short*>(&h);
}
static __device__ __forceinline__ unsigned pack2(float a, float b) {
    return (unsigned)f2bf(a) | ((unsigned)f2bf(b) << 16);
}
static __device__ __forceinline__ s4 pack4(float a, float b, float c, float d) {
    union { unsigned u[2]; s4 v; } un;
    un.u[0] = pack2(a, b);
    un.u[1] = pack2(c, d);
    return un.v;
}

// exp2 via the native trans op (K is pre-scaled by 0.25*log2(e)).
static __device__ __forceinline__ float fexp2(float x) {
#if __has_builtin(__builtin_amdgcn_exp2f)
    return __builtin_amdgcn_exp2f(x);
#else
    float r; asm("v_exp_f32 %0, %1" : "=v"(r) : "v"(x)); return r;
#endif
}

#if __has_builtin(__builtin_amdgcn_mfma_f32_16x16x16_bf16)
#define MFMA16(a, b, c) __builtin_amdgcn_mfma_f32_16x16x16_bf16(a, b, c, 0, 0, 0)
#elif __has_builtin(__builtin_amdgcn_mfma_f32_16x16x16bf16_1k)
#define MFMA16(a, b, c) __builtin_amdgcn_mfma_f32_16x16x16bf16_1k(a, b, c, 0, 0, 0)
#else
static __device__ __forceinline__ f4 mfma16_asm(s4 a, s4 b, f4 c) {
    f4 d;
    asm volatile("v_mfma_f32_16x16x16_bf16 %0, %1, %2, %3"
                 : "=&v"(d) : "v"(a), "v"(b), "v"(c));
    return d;
}
#define MFMA16(a, b, c) mfma16_asm(a, b, c)
#endif

// ---------------------------------------------------------------------------
// Kernel 1: MFMA QKV projection.  INSTRUMENTED: K-loop x REPS_PROJ, scaled
// back by 1/REPS_PROJ in the epilogue.  grid (8, 64, 3), block 256.
// ---------------------------------------------------------------------------
__global__ __launch_bounds__(256)
void proj_kernel(const float* __restrict__ x,
                 const float* __restrict__ Wq,
                 const float* __restrict__ Wk,
                 const float* __restrict__ Wv,
                 unsigned short* __restrict__ Qt,
                 unsigned short* __restrict__ Kt,
                 unsigned short* __restrict__ Vt) {
    const int lane = threadIdx.x & 63;
    const int wv   = threadIdx.x >> 6;
    const int m = lane & 15, q = lane >> 4;
    const int bh = blockIdx.y, b = bh >> 3, h = bh & 7;
    const int which = blockIdx.z;
    const int n0 = (blockIdx.x * 4 + wv) * 32;

    const float* W = (which == 0) ? Wq : (which == 1) ? Wk : Wv;
    const float* Wrow = W + ((size_t)((h * B_ + b) * DK + m)) * D_;  // A row m
    const float* xb = x + (size_t)b * D_ * L_ + n0 + m;

    f4 acc0 = {0.f, 0.f, 0.f, 0.f}, acc1 = {0.f, 0.f, 0.f, 0.f};
#pragma unroll 1
    for (int rep = 0; rep < REPS_PROJ; ++rep) {
        // launder base pointers so each rep re-executes loads + packs
        const float* Wr = Wrow;
        const float* xr = xb;
        asm volatile("" : "+v"(Wr), "+v"(xr));
#pragma unroll
        for (int kb = 0; kb < 8; ++kb) {
            const int k4 = kb * 16 + q * 4;
            float4 wf = *(const float4*)(Wr + k4);
            s4 a = pack4(wf.x, wf.y, wf.z, wf.w);

            const float* xc = xr + (size_t)k4 * L_;
            float b00 = xc[0];          float b01 = xc[L_];
            float b02 = xc[2 * L_];     float b03 = xc[3 * L_];
            float b10 = xc[16];         float b11 = xc[L_ + 16];
            float b12 = xc[2 * L_ + 16];float b13 = xc[3 * L_ + 16];
            s4 bf0 = pack4(b00, b01, b02, b03);
            s4 bf1 = pack4(b10, b11, b12, b13);

            acc0 = MFMA16(a, bf0, acc0);
            acc1 = MFMA16(a, bf1, acc1);
        }
    }
    const float rs = 1.0f / (float)REPS_PROJ;

    if (which == 2) {
        unsigned short* vp = Vt + ((size_t)bh * DK + q * 4) * L_ + n0 + m;
        vp[0]      = f2bf(acc0[0] * rs); vp[L_]     = f2bf(acc0[1] * rs);
        vp[2 * L_] = f2bf(acc0[2] * rs); vp[3 * L_] = f2bf(acc0[3] * rs);
        vp += 16;
        vp[0]      = f2bf(acc1[0] * rs); vp[L_]     = f2bf(acc1[1] * rs);
        vp[2 * L_] = f2bf(acc1[2] * rs); vp[3 * L_] = f2bf(acc1[3] * rs);
    } else {
        // 0.25 = 1/sqrt(Dk); log2(e) folded into K; rs undoes the reps.
        const float sc = ((which == 1) ? 0.25f * 1.4426950408889634f : 1.0f) * rs;
        unsigned short* T = (which == 0) ? Qt : Kt;
        uint2 u0, u1;
        u0.x = pack2(acc0[0] * sc, acc0[1] * sc);
        u0.y = pack2(acc0[2] * sc, acc0[3] * sc);
        u1.x = pack2(acc1[0] * sc, acc1[1] * sc);
        u1.y = pack2(acc1[2] * sc, acc1[3] * sc);
        *(uint2*)(T + ((size_t)bh * L_ + n0 + m) * DK + q * 4)      = u0;
        *(uint2*)(T + ((size_t)bh * L_ + n0 + 16 + m) * DK + q * 4) = u1;
    }
}

// ---------------------------------------------------------------------------
// Kernel 2: fused attention + output projection.  INSTRUMENTED: phase-1
// i-loop x REPS_ATTN (O and ls scale together; normalization cancels it).
// grid (32, 8), block 1024.
// ---------------------------------------------------------------------------
__global__ __launch_bounds__(1024)
void attn_out_kernel(const unsigned short* __restrict__ Qt,
                     const unsigned short* __restrict__ Kt,
                     const unsigned short* __restrict__ Vt,
                     const float* __restrict__ Wo,
                     float* __restrict__ out) {
    const int lane = threadIdx.x & 63;
    const int wid  = threadIdx.x >> 6;          // 0..15
    const int m = lane & 15, q = lane >> 4;
    const int b    = blockIdx.y;
    const int jblk = blockIdx.x * 32;

    const int h     = wid & 7;
    const int ihalf = wid >> 3;
    const int bh    = b * NH + h;

    __shared__ unsigned short hls[32][132];     // [l_local][d], 8.25 KB
    __shared__ float red[8][64][12];            // partial O0(4) O1(4) ls0 ls1

    // ---- Phase 1: partial attention for (head h, i-half ihalf)
    s4 bk0 = *(const s4*)(Kt + ((size_t)bh * L_ + jblk + m) * DK + q * 4);
    s4 bk1 = *(const s4*)(Kt + ((size_t)bh * L_ + jblk + 16 + m) * DK + q * 4);

    f4 O0 = {0.f, 0.f, 0.f, 0.f}, O1 = {0.f, 0.f, 0.f, 0.f};
    float ls0 = 0.f, ls1 = 0.f;
    const unsigned short* qbase = Qt + (size_t)bh * L_ * DK + q * 4
                                     + (size_t)(ihalf * (L_ / 2)) * DK;
    const unsigned short* vbase = Vt + ((size_t)bh * DK + m) * L_ + q * 4
                                     + ihalf * (L_ / 2);

#pragma unroll 1
    for (int rep = 0; rep < REPS_ATTN; ++rep) {
        const unsigned short* qb = qbase;
        const unsigned short* vb = vbase;
        asm volatile("" : "+v"(qb), "+v"(vb));
#pragma unroll 4
        for (int i0 = 0; i0 < L_ / 2; i0 += 16) {
            s4 aq = *(const s4*)(qb + (size_t)(i0 + m) * DK);
            s4 av = *(const s4*)(vb + i0);

            f4 z = {0.f, 0.f, 0.f, 0.f};
            f4 S0 = MFMA16(aq, bk0, z);     // S[i0+q*4+r][jblk+m]     (*log2e)
            f4 S1 = MFMA16(aq, bk1, z);     // S[i0+q*4+r][jblk+16+m]  (*log2e)

            float p00 = fexp2(S0[0]), p01 = fexp2(S0[1]);
            float p02 = fexp2(S0[2]), p03 = fexp2(S0[3]);
            float p10 = fexp2(S1[0]), p11 = fexp2(S1[1]);
            float p12 = fexp2(S1[2]), p13 = fexp2(S1[3]);
            ls0 += (p00 + p01) + (p02 + p03);
            ls1 += (p10 + p11) + (p12 + p13);

            s4 pb0, pb1;
            pb0[0] = (short)f2bf(p00); pb0[1] = (short)f2bf(p01);
            pb0[2] = (short)f2bf(p02); pb0[3] = (short)f2bf(p03);
            pb1[0] = (short)f2bf(p10); pb1[1] = (short)f2bf(p11);
            pb1[2] = (short)f2bf(p12); pb1[3] = (short)f2bf(p13);

            O0 = MFMA16(av, pb0, O0);       // O[v=q*4+r][col] += V*P
            O1 = MFMA16(av, pb1, O1);
        }
    }

    ls0 += __shfl_xor(ls0, 16, 64);
    ls0 += __shfl_xor(ls0, 32, 64);
    ls1 += __shfl_xor(ls1, 16, 64);
    ls1 += __shfl_xor(ls1, 32, 64);

    if (ihalf) {
        float* r = red[h][lane];
        *(f4*)(r)     = O0;
        *(f4*)(r + 4) = O1;
        r[8] = ls0; r[9] = ls1;
    }
    __syncthreads();
    if (!ihalf) {
        const float* r = red[h][lane];
        f4 P0 = *(const f4*)(r), P1 = *(const f4*)(r + 4);
        O0 += P0; O1 += P1;
        const float inv0 = 1.f / (ls0 + r[8]);   // ls doubled, O doubled -> cancels
        const float inv1 = 1.f / (ls1 + r[9]);

        uint2 o0, o1;
        o0.x = pack2(O0[0] * inv0, O0[1] * inv0);
        o0.y = pack2(O0[2] * inv0, O0[3] * inv0);
        o1.x = pack2(O1[0] * inv1, O1[1] * inv1);
        o1.y = pack2(O1[2] * inv1, O1[3] * inv1);
        *(uint2*)&hls[m][h * 16 + q * 4]      = o0;
        *(uint2*)&hls[16 + m][h * 16 + q * 4] = o1;
    }
    __syncthreads();

    // ---- Phase 2: wave -> (o-chunk, j-subtile); 8 kb steps, 1 MFMA each
    {
        const int oc = wid & 7, jt = wid >> 3;
        const int o0 = oc * 16;
        const float* Wrow = Wo + ((size_t)b * D_ + o0 + m) * D_;

        f4 acc = {0.f, 0.f, 0.f, 0.f};
#pragma unroll
        for (int kb = 0; kb < 8; ++kb) {
            const int k4 = kb * 16 + q * 4;
            float4 wf = *(const float4*)(Wrow + k4);
            s4 a  = pack4(wf.x, wf.y, wf.z, wf.w);
            s4 bb = *(const s4*)&hls[jt * 16 + m][k4];   // B[k][n=l] = hls[l][k]
            acc = MFMA16(a, bb, acc);
        }

        float* op = out + ((size_t)b * D_ + o0 + q * 4) * L_ + jblk + jt * 16 + m;
        op[0]      = acc[0]; op[L_]     = acc[1];
        op[2 * L_] = acc[2]; op[3 * L_] = acc[3];
    }
}

// ---------------------------------------------------------------------------
extern "C" void kernel_launch(void* const* d_in, const int* in_sizes, int n_in,
                              void* d_out, int out_size, void* d_ws, size_t ws_size,
                              hipStream_t stream) {
    const float* x  = (const float*)d_in[0];
    const float* Wq = (const float*)d_in[1];
    const float* Wk = (const float*)d_in[2];
    const float* Wv = (const float*)d_in[3];
    const float* Wo = (const float*)d_in[4];
    float* out = (float*)d_out;

    const size_t SEG = (size_t)B_ * NH * DK * L_;   // 1,048,576 elements
    unsigned short* Qt = (unsigned short*)d_ws;     // bf16 [bh][l][k], 2 MB
    unsigned short* Kt = Qt + SEG;                  // bf16 [bh][j][k], 2 MB
    unsigned short* Vt = Kt + SEG;                  // bf16 [bh][v][i], 2 MB

    proj_kernel<<<dim3(8, B_ * NH, 3), 256, 0, stream>>>(x, Wq, Wk, Wv, Qt, Kt, Vt);
    attn_out_kernel<<<dim3(32, B_), 1024, 0, stream>>>(Qt, Kt, Vt, Wo, out);
}

// Round 3
// 119.239 us; speedup vs baseline: 1.2569x; 1.2569x over previous
//
#include <hip/hip_runtime.h>
#include <hip/hip_bf16.h>

#define B_ 8
#define D_ 128
#define NH 8
#define L_ 1024
#define DK 16

typedef __attribute__((ext_vector_type(4))) short s4;
typedef __attribute__((ext_vector_type(4))) float f4;

static __device__ __forceinline__ unsigned short f2bf(float f) {
    __hip_bfloat16 h = __float2bfloat16(f);
    return *reinterpret_cast<unsigned short*>(&h);
}
static __device__ __forceinline__ unsigned pack2(float a, float b) {
    return (unsigned)f2bf(a) | ((unsigned)f2bf(b) << 16);
}
static __device__ __forceinline__ s4 pack4(float a, float b, float c, float d) {
    union { unsigned u[2]; s4 v; } un;
    un.u[0] = pack2(a, b);
    un.u[1] = pack2(c, d);
    return un.v;
}

// exp2 via native trans op (K pre-scaled by 0.25*log2(e) so exp(S)=exp2(S')).
static __device__ __forceinline__ float fexp2(float x) {
#if __has_builtin(__builtin_amdgcn_exp2f)
    return __builtin_amdgcn_exp2f(x);
#else
    float r; asm("v_exp_f32 %0, %1" : "=v"(r) : "v"(x)); return r;
#endif
}

// 16x16x16 bf16 MFMA: D = A*B + C.  A[m=lane&15][k=(lane>>4)*4+jj],
// B[k=(lane>>4)*4+jj][n=lane&15], C/D[row=(lane>>4)*4+reg][col=lane&15].
#if __has_builtin(__builtin_amdgcn_mfma_f32_16x16x16_bf16)
#define MFMA16(a, b, c) __builtin_amdgcn_mfma_f32_16x16x16_bf16(a, b, c, 0, 0, 0)
#elif __has_builtin(__builtin_amdgcn_mfma_f32_16x16x16bf16_1k)
#define MFMA16(a, b, c) __builtin_amdgcn_mfma_f32_16x16x16bf16_1k(a, b, c, 0, 0, 0)
#else
static __device__ __forceinline__ f4 mfma16_asm(s4 a, s4 b, f4 c) {
    f4 d;
    asm volatile("v_mfma_f32_16x16x16_bf16 %0, %1, %2, %3"
                 : "=&v"(d) : "v"(a), "v"(b), "v"(c));
    return d;
}
#define MFMA16(a, b, c) mfma16_asm(a, b, c)
#endif

// ---------------------------------------------------------------------------
// Kernel 1: FUSED QKV projection.  R2 instrumentation showed the old 3-way
// (blockIdx.z) split was issue/latency-bound (VALUBusy 25%, MfmaUtil 6%,
// HBM 3%) on 3x-redundant x gathers + packs.  Now one wave computes Q, K, V
// for a 16-wide l-tile: x fragment loaded+packed ONCE, fed to 3 MFMAs.
//   Per kb-iter: 4 x scalar loads + 1 pack4 + 3 W float4 loads + 3 pack4
//   + 3 MFMA.  x scalar loads kernel-wide: 393K -> 131K.
// grid (16, 64), block 256 (4 waves -> 4096 waves, 4 waves/SIMD).
// ---------------------------------------------------------------------------
__global__ __launch_bounds__(256)
void proj_kernel(const float* __restrict__ x,
                 const float* __restrict__ Wq,
                 const float* __restrict__ Wk,
                 const float* __restrict__ Wv,
                 unsigned short* __restrict__ Qt,
                 unsigned short* __restrict__ Kt,
                 unsigned short* __restrict__ Vt) {
    const int lane = threadIdx.x & 63;
    const int wv   = threadIdx.x >> 6;
    const int m = lane & 15, q = lane >> 4;
    const int bh = blockIdx.y, b = bh >> 3, h = bh & 7;
    const int n0 = (blockIdx.x * 4 + wv) * 16;

    const size_t wrow_off = ((size_t)((h * B_ + b) * DK + m)) * D_;  // A row m
    const float* Wqr = Wq + wrow_off;
    const float* Wkr = Wk + wrow_off;
    const float* Wvr = Wv + wrow_off;
    const float* xb = x + (size_t)b * D_ * L_ + n0 + m;

    f4 aQ = {0.f, 0.f, 0.f, 0.f}, aK = {0.f, 0.f, 0.f, 0.f}, aV = {0.f, 0.f, 0.f, 0.f};
#pragma unroll
    for (int kb = 0; kb < 8; ++kb) {
        const int k4 = kb * 16 + q * 4;

        const float* xc = xb + (size_t)k4 * L_;
        float b0 = xc[0], b1 = xc[L_], b2 = xc[2 * L_], b3 = xc[3 * L_];
        s4 bf = pack4(b0, b1, b2, b3);

        float4 wq = *(const float4*)(Wqr + k4);
        float4 wk = *(const float4*)(Wkr + k4);
        float4 wv4 = *(const float4*)(Wvr + k4);
        s4 fq = pack4(wq.x, wq.y, wq.z, wq.w);
        s4 fk = pack4(wk.x, wk.y, wk.z, wk.w);
        s4 fv = pack4(wv4.x, wv4.y, wv4.z, wv4.w);

        aQ = MFMA16(fq, bf, aQ);
        aK = MFMA16(fk, bf, aK);
        aV = MFMA16(fv, bf, aV);
    }

    // Epilogues.  C layout: [row = q*4 + r][col = m] (row = dk, col = l).
    // Qt[bh][l][k]:
    uint2 uq;
    uq.x = pack2(aQ[0], aQ[1]);
    uq.y = pack2(aQ[2], aQ[3]);
    *(uint2*)(Qt + ((size_t)bh * L_ + n0 + m) * DK + q * 4) = uq;

    // Kt[bh][j][k], scaled by 1/sqrt(Dk) * log2(e):
    const float sc = 0.25f * 1.4426950408889634f;
    uint2 uk;
    uk.x = pack2(aK[0] * sc, aK[1] * sc);
    uk.y = pack2(aK[2] * sc, aK[3] * sc);
    *(uint2*)(Kt + ((size_t)bh * L_ + n0 + m) * DK + q * 4) = uk;

    // Vt[bh][v][i]:
    unsigned short* vp = Vt + ((size_t)bh * DK + q * 4) * L_ + n0 + m;
    vp[0]      = f2bf(aV[0]); vp[L_]     = f2bf(aV[1]);
    vp[2 * L_] = f2bf(aV[2]); vp[3 * L_] = f2bf(aV[3]);
}

// ---------------------------------------------------------------------------
// Kernel 2: fused attention + output projection.  R2 showed phase-1 at
// ~11.5us vs a ~3.4us trans-pipe floor -> latency-bound at 4 waves/SIMD.
// Now: 16-wide j-blocks, 16 waves = (head h, i-half); __launch_bounds__
// (1024, 8) -> 2 blocks/CU = 8 waves/SIMD (max), per-wave chain halved.
// Phase 1: wave (h, ihalf): 32 iters of {S = Q*K (1 MFMA), p = exp2(S),
//   O += V*p (1 MFMA), ls += sum p}.  Softmax is a plain sum over i, so
//   partial (O, ls) are additive: ihalf-1 dumps to LDS, ihalf-0 merges,
//   normalizes, writes head tile -> hls.
// Phase 2: waves 0-7: out[b][o0..o0+15][jblk..jblk+15] = Wo[b] @ hls.
// grid (64, 8), block 1024.
// ---------------------------------------------------------------------------
__global__ __launch_bounds__(1024, 8)
void attn_out_kernel(const unsigned short* __restrict__ Qt,
                     const unsigned short* __restrict__ Kt,
                     const unsigned short* __restrict__ Vt,
                     const float* __restrict__ Wo,
                     float* __restrict__ out) {
    const int lane = threadIdx.x & 63;
    const int wid  = threadIdx.x >> 6;          // 0..15
    const int m = lane & 15, q = lane >> 4;
    const int b    = blockIdx.y;
    const int jblk = blockIdx.x * 16;

    const int h     = wid & 7;
    const int ihalf = wid >> 3;
    const int bh    = b * NH + h;

    __shared__ unsigned short hls[16][132];     // [l_local][d], 4.125 KB
    __shared__ float red[8][64][8];             // O(4) + ls(1), 16 KB

    // ---- Phase 1: partial attention for (head h, i-half ihalf), 16 j-cols
    s4 bk = *(const s4*)(Kt + ((size_t)bh * L_ + jblk + m) * DK + q * 4);

    f4 O = {0.f, 0.f, 0.f, 0.f};
    float ls = 0.f;
    const unsigned short* qbase = Qt + (size_t)bh * L_ * DK + q * 4
                                     + (size_t)(ihalf * (L_ / 2)) * DK;
    const unsigned short* vbase = Vt + ((size_t)bh * DK + m) * L_ + q * 4
                                     + ihalf * (L_ / 2);

#pragma unroll 2
    for (int i0 = 0; i0 < L_ / 2; i0 += 16) {
        s4 aq = *(const s4*)(qbase + (size_t)(i0 + m) * DK);
        s4 av = *(const s4*)(vbase + i0);

        f4 z = {0.f, 0.f, 0.f, 0.f};
        f4 S = MFMA16(aq, bk, z);       // S[i0+q*4+r][jblk+m]  (*log2e)

        float p0 = fexp2(S[0]), p1 = fexp2(S[1]);
        float p2 = fexp2(S[2]), p3 = fexp2(S[3]);
        ls += (p0 + p1) + (p2 + p3);

        s4 pb;
        pb[0] = (short)f2bf(p0); pb[1] = (short)f2bf(p1);
        pb[2] = (short)f2bf(p2); pb[3] = (short)f2bf(p3);

        O = MFMA16(av, pb, O);          // O[v=q*4+r][jblk+m] += V*P
    }

    ls += __shfl_xor(ls, 16, 64);
    ls += __shfl_xor(ls, 32, 64);

    if (ihalf) {
        float* r = red[h][lane];
        *(f4*)(r) = O;
        r[4] = ls;
    }
    __syncthreads();
    if (!ihalf) {
        const float* r = red[h][lane];
        f4 P = *(const f4*)(r);
        O += P;
        const float inv = 1.f / (ls + r[4]);

        // head tile row l_local = m, cols d = h*16 + q*4 + r
        uint2 o0;
        o0.x = pack2(O[0] * inv, O[1] * inv);
        o0.y = pack2(O[2] * inv, O[3] * inv);
        *(uint2*)&hls[m][h * 16 + q * 4] = o0;
    }
    __syncthreads();

    // ---- Phase 2: waves 0-7 -> o-chunk each; 8 kb steps, 1 MFMA each
    if (wid < 8) {
        const int o0 = wid * 16;
        const float* Wrow = Wo + ((size_t)b * D_ + o0 + m) * D_;

        f4 acc = {0.f, 0.f, 0.f, 0.f};
#pragma unroll
        for (int kb = 0; kb < 8; ++kb) {
            const int k4 = kb * 16 + q * 4;
            float4 wf = *(const float4*)(Wrow + k4);
            s4 a  = pack4(wf.x, wf.y, wf.z, wf.w);
            s4 bb = *(const s4*)&hls[m][k4];     // B[k][n=l] = hls[l][k]
            acc = MFMA16(a, bb, acc);
        }

        float* op = out + ((size_t)b * D_ + o0 + q * 4) * L_ + jblk + m;
        op[0]      = acc[0]; op[L_]     = acc[1];
        op[2 * L_] = acc[2]; op[3 * L_] = acc[3];
    }
}

// ---------------------------------------------------------------------------
extern "C" void kernel_launch(void* const* d_in, const int* in_sizes, int n_in,
                              void* d_out, int out_size, void* d_ws, size_t ws_size,
                              hipStream_t stream) {
    const float* x  = (const float*)d_in[0];
    const float* Wq = (const float*)d_in[1];
    const float* Wk = (const float*)d_in[2];
    const float* Wv = (const float*)d_in[3];
    const float* Wo = (const float*)d_in[4];
    float* out = (float*)d_out;

    const size_t SEG = (size_t)B_ * NH * DK * L_;   // 1,048,576 elements
    unsigned short* Qt = (unsigned short*)d_ws;     // bf16 [bh][l][k], 2 MB
    unsigned short* Kt = Qt + SEG;                  // bf16 [bh][j][k], 2 MB
    unsigned short* Vt = Kt + SEG;                  // bf16 [bh][v][i], 2 MB

    proj_kernel<<<dim3(16, B_ * NH), 256, 0, stream>>>(x, Wq, Wk, Wv, Qt, Kt, Vt);
    attn_out_kernel<<<dim3(64, B_), 1024, 0, stream>>>(Qt, Kt, Vt, Wo, out);
}

// Round 4
// 101.243 us; speedup vs baseline: 1.4803x; 1.1778x over previous
//
#include <hip/hip_runtime.h>
#include <hip/hip_bf16.h>

#define B_ 8
#define D_ 128
#define NH 8
#define L_ 1024
#define DK 16

typedef __attribute__((ext_vector_type(4))) short s4;
typedef __attribute__((ext_vector_type(4))) float f4;

static __device__ __forceinline__ unsigned short f2bf(float f) {
    __hip_bfloat16 h = __float2bfloat16(f);
    return *reinterpret_cast<unsigned short*>(&h);
}
static __device__ __forceinline__ unsigned pack2(float a, float b) {
    return (unsigned)f2bf(a) | ((unsigned)f2bf(b) << 16);
}
static __device__ __forceinline__ s4 pack4(float a, float b, float c, float d) {
    union { unsigned u[2]; s4 v; } un;
    un.u[0] = pack2(a, b);
    un.u[1] = pack2(c, d);
    return un.v;
}

// exp2 via native trans op (K pre-scaled by 0.25*log2(e) so exp(S)=exp2(S')).
static __device__ __forceinline__ float fexp2(float x) {
#if __has_builtin(__builtin_amdgcn_exp2f)
    return __builtin_amdgcn_exp2f(x);
#else
    float r; asm("v_exp_f32 %0, %1" : "=v"(r) : "v"(x)); return r;
#endif
}

// 16x16x16 bf16 MFMA: D = A*B + C.  A[m=lane&15][k=(lane>>4)*4+jj],
// B[k=(lane>>4)*4+jj][n=lane&15], C/D[row=(lane>>4)*4+reg][col=lane&15].
#if __has_builtin(__builtin_amdgcn_mfma_f32_16x16x16_bf16)
#define MFMA16(a, b, c) __builtin_amdgcn_mfma_f32_16x16x16_bf16(a, b, c, 0, 0, 0)
#elif __has_builtin(__builtin_amdgcn_mfma_f32_16x16x16bf16_1k)
#define MFMA16(a, b, c) __builtin_amdgcn_mfma_f32_16x16x16bf16_1k(a, b, c, 0, 0, 0)
#else
static __device__ __forceinline__ f4 mfma16_asm(s4 a, s4 b, f4 c) {
    f4 d;
    asm volatile("v_mfma_f32_16x16x16_bf16 %0, %1, %2, %3"
                 : "=&v"(d) : "v"(a), "v"(b), "v"(c));
    return d;
}
#define MFMA16(a, b, c) mfma16_asm(a, b, c)
#endif

// ---------------------------------------------------------------------------
// Kernel 1: FUSED QKV projection (unchanged from R3 -- measured ~3-7us).
// One wave computes Q, K, V for a 16-wide l-tile: x fragment loaded+packed
// ONCE, fed to 3 MFMAs.  grid (16, 64), block 256.
// ---------------------------------------------------------------------------
__global__ __launch_bounds__(256)
void proj_kernel(const float* __restrict__ x,
                 const float* __restrict__ Wq,
                 const float* __restrict__ Wk,
                 const float* __restrict__ Wv,
                 unsigned short* __restrict__ Qt,
                 unsigned short* __restrict__ Kt,
                 unsigned short* __restrict__ Vt) {
    const int lane = threadIdx.x & 63;
    const int wv   = threadIdx.x >> 6;
    const int m = lane & 15, q = lane >> 4;
    const int bh = blockIdx.y, b = bh >> 3, h = bh & 7;
    const int n0 = (blockIdx.x * 4 + wv) * 16;

    const size_t wrow_off = ((size_t)((h * B_ + b) * DK + m)) * D_;  // A row m
    const float* Wqr = Wq + wrow_off;
    const float* Wkr = Wk + wrow_off;
    const float* Wvr = Wv + wrow_off;
    const float* xb = x + (size_t)b * D_ * L_ + n0 + m;

    f4 aQ = {0.f, 0.f, 0.f, 0.f}, aK = {0.f, 0.f, 0.f, 0.f}, aV = {0.f, 0.f, 0.f, 0.f};
#pragma unroll
    for (int kb = 0; kb < 8; ++kb) {
        const int k4 = kb * 16 + q * 4;

        const float* xc = xb + (size_t)k4 * L_;
        float b0 = xc[0], b1 = xc[L_], b2 = xc[2 * L_], b3 = xc[3 * L_];
        s4 bf = pack4(b0, b1, b2, b3);

        float4 wq = *(const float4*)(Wqr + k4);
        float4 wk = *(const float4*)(Wkr + k4);
        float4 wv4 = *(const float4*)(Wvr + k4);
        s4 fq = pack4(wq.x, wq.y, wq.z, wq.w);
        s4 fk = pack4(wk.x, wk.y, wk.z, wk.w);
        s4 fv = pack4(wv4.x, wv4.y, wv4.z, wv4.w);

        aQ = MFMA16(fq, bf, aQ);
        aK = MFMA16(fk, bf, aK);
        aV = MFMA16(fv, bf, aV);
    }

    // Epilogues.  C layout: [row = q*4 + r][col = m] (row = dk, col = l).
    uint2 uq;
    uq.x = pack2(aQ[0], aQ[1]);
    uq.y = pack2(aQ[2], aQ[3]);
    *(uint2*)(Qt + ((size_t)bh * L_ + n0 + m) * DK + q * 4) = uq;

    const float sc = 0.25f * 1.4426950408889634f;   // 1/sqrt(Dk) * log2(e)
    uint2 uk;
    uk.x = pack2(aK[0] * sc, aK[1] * sc);
    uk.y = pack2(aK[2] * sc, aK[3] * sc);
    *(uint2*)(Kt + ((size_t)bh * L_ + n0 + m) * DK + q * 4) = uk;

    unsigned short* vp = Vt + ((size_t)bh * DK + q * 4) * L_ + n0 + m;
    vp[0]      = f2bf(aV[0]); vp[L_]     = f2bf(aV[1]);
    vp[2 * L_] = f2bf(aV[2]); vp[3 * L_] = f2bf(aV[3]);
}

// ---------------------------------------------------------------------------
// Kernel 2: fused attention + output projection.  ROUND-1 SHAPE RESTORED:
// 32-wide j-tiles, grid (32,8), block 1024 = 16 waves (h, ihalf), 4 waves/
// SIMD, NO min-waves launch_bounds clamp (R3's (1024,8) forced VGPR=28 ->
// no pipelining -> 45.9us; latency-bound chain needs registers, not TLP).
// New vs round 1:
//   (a) softmax denominator via ones-row MFMA: L = MFMA(ones, pb, L)
//       accumulates column-sums of P on the idle matrix pipe; kills ~12
//       VALU adds/iter + 4 shfl reduces.  Every lane ends with ls for its
//       column in L[0].
//   (b) explicit next-iter prefetch of aq/av (clamped, always in-bounds)
//       to overlap L2 latency with MFMA/exp work.
// ---------------------------------------------------------------------------
__global__ __launch_bounds__(1024)
void attn_out_kernel(const unsigned short* __restrict__ Qt,
                     const unsigned short* __restrict__ Kt,
                     const unsigned short* __restrict__ Vt,
                     const float* __restrict__ Wo,
                     float* __restrict__ out) {
    const int lane = threadIdx.x & 63;
    const int wid  = threadIdx.x >> 6;          // 0..15
    const int m = lane & 15, q = lane >> 4;
    const int b    = blockIdx.y;
    const int jblk = blockIdx.x * 32;

    const int h     = wid & 7;
    const int ihalf = wid >> 3;
    const int bh    = b * NH + h;

    __shared__ unsigned short hls[32][132];     // [l_local][d], 8.25 KB
    __shared__ float red[8][64][12];            // O0(4) O1(4) ls0 ls1

    // ---- Phase 1: partial attention for (head h, i-half ihalf), 32 j-cols
    s4 bk0 = *(const s4*)(Kt + ((size_t)bh * L_ + jblk + m) * DK + q * 4);
    s4 bk1 = *(const s4*)(Kt + ((size_t)bh * L_ + jblk + 16 + m) * DK + q * 4);

    s4 ones;    // bf16 1.0 in all 4 slots (A-row of ones -> column sums)
    ones[0] = ones[1] = ones[2] = ones[3] = (short)0x3F80;

    f4 O0 = {0.f, 0.f, 0.f, 0.f}, O1 = {0.f, 0.f, 0.f, 0.f};
    f4 L0 = {0.f, 0.f, 0.f, 0.f}, L1 = {0.f, 0.f, 0.f, 0.f};
    const unsigned short* qbase = Qt + (size_t)bh * L_ * DK + q * 4
                                     + (size_t)(ihalf * (L_ / 2)) * DK;
    const unsigned short* vbase = Vt + ((size_t)bh * DK + m) * L_ + q * 4
                                     + ihalf * (L_ / 2);

    s4 aq = *(const s4*)(qbase + (size_t)m * DK);
    s4 av = *(const s4*)(vbase);

#pragma unroll 4
    for (int i0 = 0; i0 < L_ / 2; i0 += 16) {
        const int ip = (i0 + 16 < L_ / 2) ? (i0 + 16) : i0;   // clamped prefetch
        s4 aq_n = *(const s4*)(qbase + (size_t)(ip + m) * DK);
        s4 av_n = *(const s4*)(vbase + ip);

        f4 z = {0.f, 0.f, 0.f, 0.f};
        f4 S0 = MFMA16(aq, bk0, z);     // S[i0+q*4+r][jblk+m]     (*log2e)
        f4 S1 = MFMA16(aq, bk1, z);     // S[i0+q*4+r][jblk+16+m]  (*log2e)

        float p00 = fexp2(S0[0]), p01 = fexp2(S0[1]);
        float p02 = fexp2(S0[2]), p03 = fexp2(S0[3]);
        float p10 = fexp2(S1[0]), p11 = fexp2(S1[1]);
        float p12 = fexp2(S1[2]), p13 = fexp2(S1[3]);

        s4 pb0, pb1;
        pb0[0] = (short)f2bf(p00); pb0[1] = (short)f2bf(p01);
        pb0[2] = (short)f2bf(p02); pb0[3] = (short)f2bf(p03);
        pb1[0] = (short)f2bf(p10); pb1[1] = (short)f2bf(p11);
        pb1[2] = (short)f2bf(p12); pb1[3] = (short)f2bf(p13);

        O0 = MFMA16(av, pb0, O0);       // O[v=q*4+r][col] += V*P
        O1 = MFMA16(av, pb1, O1);
        L0 = MFMA16(ones, pb0, L0);     // col-sums of P (softmax denom)
        L1 = MFMA16(ones, pb1, L1);

        aq = aq_n; av = av_n;
    }

    // Every lane: L0[0] = sum_i P[i][jblk+m], L1[0] = sum_i P[i][jblk+16+m].
    if (ihalf) {
        float* r = red[h][lane];
        *(f4*)(r)     = O0;
        *(f4*)(r + 4) = O1;
        r[8] = L0[0]; r[9] = L1[0];
    }
    __syncthreads();
    if (!ihalf) {
        const float* r = red[h][lane];
        f4 P0 = *(const f4*)(r), P1 = *(const f4*)(r + 4);
        O0 += P0; O1 += P1;
        const float inv0 = 1.f / (L0[0] + r[8]);
        const float inv1 = 1.f / (L1[0] + r[9]);

        // head tile rows l_local = {m, 16+m}, cols d = h*16 + q*4 + r
        uint2 o0, o1;
        o0.x = pack2(O0[0] * inv0, O0[1] * inv0);
        o0.y = pack2(O0[2] * inv0, O0[3] * inv0);
        o1.x = pack2(O1[0] * inv1, O1[1] * inv1);
        o1.y = pack2(O1[2] * inv1, O1[3] * inv1);
        *(uint2*)&hls[m][h * 16 + q * 4]      = o0;
        *(uint2*)&hls[16 + m][h * 16 + q * 4] = o1;
    }
    __syncthreads();

    // ---- Phase 2: wave -> (o-chunk, j-subtile); 8 kb steps, 1 MFMA each
    {
        const int oc = wid & 7, jt = wid >> 3;
        const int o0 = oc * 16;
        const float* Wrow = Wo + ((size_t)b * D_ + o0 + m) * D_;

        f4 acc = {0.f, 0.f, 0.f, 0.f};
#pragma unroll
        for (int kb = 0; kb < 8; ++kb) {
            const int k4 = kb * 16 + q * 4;
            float4 wf = *(const float4*)(Wrow + k4);
            s4 a  = pack4(wf.x, wf.y, wf.z, wf.w);
            s4 bb = *(const s4*)&hls[jt * 16 + m][k4];   // B[k][n=l] = hls[l][k]
            acc = MFMA16(a, bb, acc);
        }

        float* op = out + ((size_t)b * D_ + o0 + q * 4) * L_ + jblk + jt * 16 + m;
        op[0]      = acc[0]; op[L_]     = acc[1];
        op[2 * L_] = acc[2]; op[3 * L_] = acc[3];
    }
}

// ---------------------------------------------------------------------------
extern "C" void kernel_launch(void* const* d_in, const int* in_sizes, int n_in,
                              void* d_out, int out_size, void* d_ws, size_t ws_size,
                              hipStream_t stream) {
    const float* x  = (const float*)d_in[0];
    const float* Wq = (const float*)d_in[1];
    const float* Wk = (const float*)d_in[2];
    const float* Wv = (const float*)d_in[3];
    const float* Wo = (const float*)d_in[4];
    float* out = (float*)d_out;

    const size_t SEG = (size_t)B_ * NH * DK * L_;   // 1,048,576 elements
    unsigned short* Qt = (unsigned short*)d_ws;     // bf16 [bh][l][k], 2 MB
    unsigned short* Kt = Qt + SEG;                  // bf16 [bh][j][k], 2 MB
    unsigned short* Vt = Kt + SEG;                  // bf16 [bh][v][i], 2 MB

    proj_kernel<<<dim3(16, B_ * NH), 256, 0, stream>>>(x, Wq, Wk, Wv, Qt, Kt, Vt);
    attn_out_kernel<<<dim3(32, B_), 1024, 0, stream>>>(Qt, Kt, Vt, Wo, out);
}